// Round 23
// baseline (31.743 us; speedup 1.0000x reference)
//
#include <hip/hip_runtime.h>

#define H 512
#define W 512
#define BAND 64
#define NBANDS (H / BAND)   // 8
#define NBLK (NBANDS * 32 * 2)  // 512 blocks
#define NEG_INF (-3.402823466e38f)

// DPP wave shifts: wave_shr1 (0x138) = shfl_up by 1 (old = lane-0 fill);
// wave_shl1 (0x130) = shfl_down by 1 (old = lane-63 fill). Pure VALU.
__device__ __forceinline__ float dpp_up1(float x, float fill) {
    return __int_as_float(__builtin_amdgcn_update_dpp(
        __float_as_int(fill), __float_as_int(x), 0x138, 0xF, 0xF, false));
}
__device__ __forceinline__ float dpp_down1(float x, float fill) {
    return __int_as_float(__builtin_amdgcn_update_dpp(
        __float_as_int(fill), __float_as_int(x), 0x130, 0xF, 0xF, false));
}

// R22 structure (best: 24.9us) + R23: software-pipeline WITHIN the iteration:
// issue batch b's 8 float4 loads -> run stage C for batch b-1 (pure LDS+VALU,
// ~300cyc) -> consume loads (ROWTAIL) -> barrier. Hides the batch-start
// L1/L2/HBM latency that made dur ~= SUM of pipes. No register state crosses
// a barrier (loads issued and consumed in the same iteration) -> the R18/R21
// prefetch failure modes (double-fetch, vmcnt-drain serialization) cannot
// occur: same loads, same count, just reordered against stage C.
// Double-buffer check: stageC(b-1) reads hbuf[(b-1)&1]; next write to that
// buffer is iter b+1, after iter b's barrier. Epilogue: stageC(batch 4).
// Proven core (R19/R20/R22): wave owns contiguous pair (2w,2w+1); 8 float4
// loads/pair; shared middle partial; s = 3-sum via 2 DPP halos (9x-scaled);
// horizontal 17-max via suffix/prefix + 16 DPP shifts; vertical 17-max via
// per-column register van Herk (arr[16], batch == segment); per-block partial
// (no atomic, no zero-kernel); 1D grid id = band*64 + (img*2+t) so id%8
// (XCD) is constant across bands -> halo rows L2-hit.
// Lessons: (R12/R13) spills -> `#pragma unroll 1` + (512,4); (R16) extra
// barrier regressed; (R18/R21) cross-barrier prefetch double-fetches.
// hbuf split-half: k=0..3 at [4L], k=4..7 at [256+4L]; conflict-free.
__global__ __launch_bounds__(512, 4) void fused_kernel(const float* __restrict__ in0,
                                                       const float* __restrict__ in1,
                                                       double* __restrict__ partial) {
    const int id   = blockIdx.x;
    const int band = id >> 6;            // 0..7
    const int u    = id & 63;            // (img*2 + tensor)
    const int img  = u >> 1;
    const float* __restrict__ im = ((u & 1) ? in1 : in0) + (size_t)img * H * W;

    const int y0 = band * BAND, y1 = y0 + BAND;
    const int jlo_v = y0 - 8;            // first streamed s-row (even)

    __shared__ float hbuf[2][16][W];     // double-buffered h rows (split-half)
    __shared__ double wsum[8];

    const int tid  = threadIdx.x;
    const int w    = tid >> 6;           // wave id 0..7
    const int lane = tid & 63;
    const int c0   = lane << 3;          // 8 cols per lane
    // split-half position of column tid inside an hbuf row
    const int pos  = ((tid & 4) ? 256 : 0) + ((tid >> 3) << 2) + (tid & 3);

    // per-col horizontal window weights (hoisted; includes /289)
    float cw[8];
#pragma unroll
    for (int k = 0; k < 8; ++k) {
        const int col = c0 + k;
        const int wlo = (col - 8 > 0) ? col - 8 : 0;
        const int whi = (col + 8 < W - 1) ? col + 8 : W - 1;
        cw[k] = (float)(whi - wlo + 1) * (1.f / 289.f);
    }

    float accMax = 0.f, accSum = 0.f;
    float arr[16];                       // van Herk: prev-seg suffix / cur h

// Per-row tail: from t[8] (3-row raw sum) compute s, accSum, h, write hbuf.
#define ROWTAIL(T, J, SLOT)                                                    \
    {                                                                          \
        const float tl = dpp_up1((T)[7], 0.f);                                 \
        const float tr = dpp_down1((T)[0], 0.f);                               \
        float s[8];                                                            \
        s[0] = tl + (T)[0] + (T)[1];                                           \
        _Pragma("unroll") for (int k = 1; k < 7; ++k)                          \
            s[k] = (T)[k - 1] + (T)[k] + (T)[k + 1];                           \
        s[7] = (T)[6] + (T)[7] + tr;                                           \
        const int rlo = ((J) - 8 > y0) ? (J) - 8 : y0;                         \
        const int rhi = ((J) + 8 < y1 - 1) ? (J) + 8 : y1 - 1;                 \
        float rowsum = 0.f;                                                    \
        _Pragma("unroll") for (int k = 0; k < 8; ++k)                          \
            rowsum += s[k] * cw[k];                                            \
        accSum += rowsum * (float)(rhi - rlo + 1);                             \
        float p[8], qarr[8];                                                   \
        p[0] = s[0];                                                           \
        _Pragma("unroll") for (int k = 1; k < 8; ++k)                          \
            p[k] = fmaxf(p[k - 1], s[k]);                                      \
        qarr[7] = s[7];                                                        \
        _Pragma("unroll") for (int k = 6; k >= 0; --k)                         \
            qarr[k] = fmaxf(qarr[k + 1], s[k]);                                \
        const float m = p[7];                                                  \
        float h[8];                                                            \
        _Pragma("unroll") for (int k = 0; k < 8; ++k) {                        \
            const float qp = dpp_up1(qarr[k], NEG_INF);                        \
            const float pn = dpp_down1(p[k], NEG_INF);                         \
            h[k] = fmaxf(fmaxf(qp, m), pn);                                    \
        }                                                                      \
        float* hw = hwbase + (SLOT) * W;                                       \
        *(float4*)&hw[lane << 2]         = make_float4(h[0], h[1], h[2], h[3]); \
        *(float4*)&hw[256 + (lane << 2)] = make_float4(h[4], h[5], h[6], h[7]); \
    }

// Stage C for batch BB (reads hbuf[(BB)&1]); EMIT = whether outputs exist.
#define STAGEC(BB, EMIT)                                                       \
    {                                                                          \
        const float* hb = &hbuf[(BB) & 1][0][0];                               \
        float Pblk = NEG_INF;                                                  \
        if (EMIT) {                                                            \
            _Pragma("unroll") for (int r = 0; r < 16; ++r) {                   \
                const float hv = hb[r * W + pos];                              \
                Pblk = fmaxf(Pblk, hv);                                        \
                accMax += fmaxf(arr[r], Pblk);                                 \
                arr[r] = hv;                                                   \
            }                                                                  \
        } else {                                                               \
            _Pragma("unroll") for (int r = 0; r < 16; ++r) {                   \
                const float hv = hb[r * W + pos];                              \
                Pblk = fmaxf(Pblk, hv);                                        \
                arr[r] = hv;                                                   \
            }                                                                  \
        }                                                                      \
        _Pragma("unroll") for (int rr = 14; rr >= 0; --rr)                     \
            arr[rr] = fmaxf(arr[rr], arr[rr + 1]);                             \
    }

#pragma unroll 1
    for (int b = 0; b < 5; ++b) {        // 5 batches of 16 s-rows = 80 rows
        const int jb = jlo_v + b * 16;
        float* hwbase = &hbuf[b & 1][0][0];
        const int j0 = jb + 2 * w;       // wave's contiguous pair (j0 even)
        const int j1 = j0 + 1;
        const bool real = (j0 >= 0) && (j0 < H);  // pair never straddles

        // ---- 1) issue this batch's loads (consumed after stage C) ----
        float4 a0, b0, a1, b1, a2, b2, a3, b3;
        if (real) {
            const float* rp1 = im + (size_t)j0 * W + c0;          // row j0
            a1 = *(const float4*)rp1;  b1 = *(const float4*)(rp1 + 4);
            const float* rp2 = im + (size_t)j1 * W + c0;          // row j1
            a2 = *(const float4*)rp2;  b2 = *(const float4*)(rp2 + 4);
            if (j0 - 1 >= 0) {
                const float* rp0 = im + (size_t)(j0 - 1) * W + c0; // row j0-1
                a0 = *(const float4*)rp0;  b0 = *(const float4*)(rp0 + 4);
            } else {
                a0 = make_float4(0.f, 0.f, 0.f, 0.f);  b0 = a0;
            }
            if (j1 + 1 < H) {
                const float* rp3 = im + (size_t)(j1 + 1) * W + c0; // row j1+1
                a3 = *(const float4*)rp3;  b3 = *(const float4*)(rp3 + 4);
            } else {
                a3 = make_float4(0.f, 0.f, 0.f, 0.f);  b3 = a3;
            }
        }

        // ---- 2) stage C for previous batch (covers load latency) ----
        if (b >= 1) STAGEC(b - 1, b >= 2)

        // ---- 3) consume loads -> ROWTAILs -> write hbuf[b&1] ----
        if (real) {
            const float v0[8] = {a0.x, a0.y, a0.z, a0.w, b0.x, b0.y, b0.z, b0.w};
            const float v1[8] = {a1.x, a1.y, a1.z, a1.w, b1.x, b1.y, b1.z, b1.w};
            const float v2[8] = {a2.x, a2.y, a2.z, a2.w, b2.x, b2.y, b2.z, b2.w};
            const float v3[8] = {a3.x, a3.y, a3.z, a3.w, b3.x, b3.y, b3.z, b3.w};
            float t0[8], t1[8];
#pragma unroll
            for (int k = 0; k < 8; ++k) {
                const float mid = v1[k] + v2[k];
                t0[k] = v0[k] + mid;
                t1[k] = mid + v3[k];
            }
            ROWTAIL(t0, j0, 2 * w)
            ROWTAIL(t1, j1, 2 * w + 1)
        } else {                         // virtual pair
            const float4 ninf = make_float4(NEG_INF, NEG_INF, NEG_INF, NEG_INF);
            float* hw = hwbase + (2 * w) * W;
            *(float4*)&hw[lane << 2]         = ninf;
            *(float4*)&hw[256 + (lane << 2)] = ninf;
            hw += W;
            *(float4*)&hw[lane << 2]         = ninf;
            *(float4*)&hw[256 + (lane << 2)] = ninf;
        }
        __syncthreads();                  // the ONLY barrier per batch
    }
    // ---- epilogue: stage C for batch 4 ----
    STAGEC(4, true)
#undef ROWTAIL
#undef STAGEC

    // ---- block reduction -> per-block partial (plain store, no atomic) ----
    double v = ((double)accMax - (double)accSum) * (1.0 / 9.0);
#pragma unroll
    for (int off = 32; off > 0; off >>= 1) v += __shfl_down(v, off, 64);
    if (lane == 0) wsum[w] = v;
    __syncthreads();
    if (tid == 0) {
        double bsum = 0.0;
#pragma unroll
        for (int wv = 0; wv < 8; ++wv) bsum += wsum[wv];
        partial[id] = bsum;              // written every call: deterministic
    }
}

__global__ __launch_bounds__(512) void finalize_kernel(const double* __restrict__ partial,
                                                       float* __restrict__ out) {
    __shared__ double wsum[8];
    const int tid = threadIdx.x;
    double v = partial[tid];             // 512 partials, one per block
#pragma unroll
    for (int off = 32; off > 0; off >>= 1) v += __shfl_down(v, off, 64);
    if ((tid & 63) == 0) wsum[tid >> 6] = v;
    __syncthreads();
    if (tid == 0) {
        double s = 0.0;
#pragma unroll
        for (int wv = 0; wv < 8; ++wv) s += wsum[wv];
        // total pixels across both tensors = 2*32*512*512 = 16777216
        out[0] = (float)(1.0 - s * (1.0 / 16777216.0));
    }
}

extern "C" void kernel_launch(void* const* d_in, const int* in_sizes, int n_in,
                              void* d_out, int out_size, void* d_ws, size_t ws_size,
                              hipStream_t stream) {
    const float* in0 = (const float*)d_in[0];
    const float* in1 = (const float*)d_in[1];
    float* out = (float*)d_out;
    double* partial = (double*)d_ws;     // 512 doubles = 4 KB

    fused_kernel<<<NBLK, 512, 0, stream>>>(in0, in1, partial);
    finalize_kernel<<<1, 512, 0, stream>>>(partial, out);
}

// Round 24
// 25.222 us; speedup vs baseline: 1.2585x; 1.2585x over previous
//
#include <hip/hip_runtime.h>

#define H 512
#define W 512
#define BAND 64
#define NBANDS (H / BAND)   // 8
#define NBLK (NBANDS * 32 * 2)  // 512 blocks
#define NEG_INF (-3.402823466e38f)

// DPP wave shifts: wave_shr1 (0x138) = shfl_up by 1 (old = lane-0 fill);
// wave_shl1 (0x130) = shfl_down by 1 (old = lane-63 fill). Pure VALU.
__device__ __forceinline__ float dpp_up1(float x, float fill) {
    return __int_as_float(__builtin_amdgcn_update_dpp(
        __float_as_int(fill), __float_as_int(x), 0x138, 0xF, 0xF, false));
}
__device__ __forceinline__ float dpp_down1(float x, float fill) {
    return __int_as_float(__builtin_amdgcn_update_dpp(
        __float_as_int(fill), __float_as_int(x), 0x130, 0xF, 0xF, false));
}

// R22 EXACT structure (proven best: 24.9us) + cw[] hoist (R23's one safe bit).
// R23 lesson (reverted): holding the batch's 8 float4 loads live across
// stage C spilled (WRITE_SIZE 16B -> 10.2MB, VGPR 52->64, dur 24.9->31.7).
// Three overlap attempts all failed with counter signatures: R18 dummy-LDS
// prefetch (double-fetch), R21 cross-barrier regs (double-fetch + occupancy),
// R23 intra-iteration regs (spill) -> load latency here is cheaper eaten
// than hidden.
// Core: one block per (band, img, tensor); 512 thr = 8 waves; batches of 16
// s-rows; wave owns contiguous pair (2w, 2w+1): 8 float4 loads/pair (halo
// rows shared with sibling waves -> L1/L2 hits), shared middle partial;
// s = 3-sum via 2 DPP halos (9x-scaled); horizontal 17-max via suffix q[8] /
// prefix p[8] + 16 DPP shifts: h(8L+k) = max(q_{L-1}[k], m_L, p_{L+1}[k]);
// vertical 17-max: batch == van Herk segment, h rows -> double-buffered hbuf
// (ONE __syncthreads per batch), per-column register van Herk (arr[16]).
// Per-block partial store (no atomic, no zero-kernel). 1D grid id =
// band*64 + (img*2+t): id%8 (XCD) constant across bands -> halos L2-hit.
// (R12/R13): `#pragma unroll 1` + (512,4) -> no spill. (R16): extra barrier
// regressed. hbuf split-half: k=0..3 at [4L], k=4..7 at [256+4L]; conflict-free.
__global__ __launch_bounds__(512, 4) void fused_kernel(const float* __restrict__ in0,
                                                       const float* __restrict__ in1,
                                                       double* __restrict__ partial) {
    const int id   = blockIdx.x;
    const int band = id >> 6;            // 0..7
    const int u    = id & 63;            // (img*2 + tensor)
    const int img  = u >> 1;
    const float* __restrict__ im = ((u & 1) ? in1 : in0) + (size_t)img * H * W;

    const int y0 = band * BAND, y1 = y0 + BAND;
    const int jlo_v = y0 - 8;            // first streamed s-row (even)

    __shared__ float hbuf[2][16][W];     // double-buffered h rows (split-half)
    __shared__ double wsum[8];

    const int tid  = threadIdx.x;
    const int w    = tid >> 6;           // wave id 0..7
    const int lane = tid & 63;
    const int c0   = lane << 3;          // 8 cols per lane
    // split-half position of column tid inside an hbuf row
    const int pos  = ((tid & 4) ? 256 : 0) + ((tid >> 3) << 2) + (tid & 3);

    // per-col horizontal window weights (hoisted; includes /289)
    float cw[8];
#pragma unroll
    for (int k = 0; k < 8; ++k) {
        const int col = c0 + k;
        const int wlo = (col - 8 > 0) ? col - 8 : 0;
        const int whi = (col + 8 < W - 1) ? col + 8 : W - 1;
        cw[k] = (float)(whi - wlo + 1) * (1.f / 289.f);
    }

    float accMax = 0.f, accSum = 0.f;
    float arr[16];                       // van Herk: prev-seg suffix / cur h

// Per-row tail: from t[8] (3-row raw sum) compute s, accSum, h, write hbuf.
#define ROWTAIL(T, J, SLOT)                                                    \
    {                                                                          \
        const float tl = dpp_up1((T)[7], 0.f);                                 \
        const float tr = dpp_down1((T)[0], 0.f);                               \
        float s[8];                                                            \
        s[0] = tl + (T)[0] + (T)[1];                                           \
        _Pragma("unroll") for (int k = 1; k < 7; ++k)                          \
            s[k] = (T)[k - 1] + (T)[k] + (T)[k + 1];                           \
        s[7] = (T)[6] + (T)[7] + tr;                                           \
        const int rlo = ((J) - 8 > y0) ? (J) - 8 : y0;                         \
        const int rhi = ((J) + 8 < y1 - 1) ? (J) + 8 : y1 - 1;                 \
        float rowsum = 0.f;                                                    \
        _Pragma("unroll") for (int k = 0; k < 8; ++k)                          \
            rowsum += s[k] * cw[k];                                            \
        accSum += rowsum * (float)(rhi - rlo + 1);                             \
        float p[8], qarr[8];                                                   \
        p[0] = s[0];                                                           \
        _Pragma("unroll") for (int k = 1; k < 8; ++k)                          \
            p[k] = fmaxf(p[k - 1], s[k]);                                      \
        qarr[7] = s[7];                                                        \
        _Pragma("unroll") for (int k = 6; k >= 0; --k)                         \
            qarr[k] = fmaxf(qarr[k + 1], s[k]);                                \
        const float m = p[7];                                                  \
        float h[8];                                                            \
        _Pragma("unroll") for (int k = 0; k < 8; ++k) {                        \
            const float qp = dpp_up1(qarr[k], NEG_INF);                        \
            const float pn = dpp_down1(p[k], NEG_INF);                         \
            h[k] = fmaxf(fmaxf(qp, m), pn);                                    \
        }                                                                      \
        float* hw = hwbase + (SLOT) * W;                                       \
        *(float4*)&hw[lane << 2]         = make_float4(h[0], h[1], h[2], h[3]); \
        *(float4*)&hw[256 + (lane << 2)] = make_float4(h[4], h[5], h[6], h[7]); \
    }

#pragma unroll 1
    for (int b = 0; b < 5; ++b) {        // 5 batches of 16 s-rows = 80 rows
        const int jb = jlo_v + b * 16;
        float* hwbase = &hbuf[b & 1][0][0];

        const int j0 = jb + 2 * w;       // wave's contiguous pair (j0 even)
        const int j1 = j0 + 1;
        if (j0 >= 0 && j0 < H) {         // pair entirely real (never straddles)
            // ---- shared loads: raw rows j0-1 .. j0+2 (4 rows, 8 float4) ----
            float v0[8], v1[8], v2[8], v3[8];
            {
                const float* rp = im + (size_t)j0 * W + c0;        // row j0
                const float4 a = *(const float4*)rp;
                const float4 c4 = *(const float4*)(rp + 4);
                v1[0]=a.x; v1[1]=a.y; v1[2]=a.z; v1[3]=a.w;
                v1[4]=c4.x; v1[5]=c4.y; v1[6]=c4.z; v1[7]=c4.w;
            }
            {
                const float* rp = im + (size_t)j1 * W + c0;        // row j1
                const float4 a = *(const float4*)rp;
                const float4 c4 = *(const float4*)(rp + 4);
                v2[0]=a.x; v2[1]=a.y; v2[2]=a.z; v2[3]=a.w;
                v2[4]=c4.x; v2[5]=c4.y; v2[6]=c4.z; v2[7]=c4.w;
            }
            if (j0 - 1 >= 0) {
                const float* rp = im + (size_t)(j0 - 1) * W + c0;  // row j0-1
                const float4 a = *(const float4*)rp;
                const float4 c4 = *(const float4*)(rp + 4);
                v0[0]=a.x; v0[1]=a.y; v0[2]=a.z; v0[3]=a.w;
                v0[4]=c4.x; v0[5]=c4.y; v0[6]=c4.z; v0[7]=c4.w;
            } else {
#pragma unroll
                for (int k = 0; k < 8; ++k) v0[k] = 0.f;
            }
            if (j1 + 1 < H) {
                const float* rp = im + (size_t)(j1 + 1) * W + c0;  // row j1+1
                const float4 a = *(const float4*)rp;
                const float4 c4 = *(const float4*)(rp + 4);
                v3[0]=a.x; v3[1]=a.y; v3[2]=a.z; v3[3]=a.w;
                v3[4]=c4.x; v3[5]=c4.y; v3[6]=c4.z; v3[7]=c4.w;
            } else {
#pragma unroll
                for (int k = 0; k < 8; ++k) v3[k] = 0.f;
            }
            // ---- shared middle partial: t0 = v0+v1+v2, t1 = v1+v2+v3 ----
            float t0[8], t1[8];
#pragma unroll
            for (int k = 0; k < 8; ++k) {
                const float mid = v1[k] + v2[k];
                t0[k] = v0[k] + mid;
                t1[k] = mid + v3[k];
            }
            ROWTAIL(t0, j0, 2 * w)
            ROWTAIL(t1, j1, 2 * w + 1)
        } else {                         // virtual pair
            const float4 ninf = make_float4(NEG_INF, NEG_INF, NEG_INF, NEG_INF);
            float* hw = hwbase + (2 * w) * W;
            *(float4*)&hw[lane << 2]         = ninf;
            *(float4*)&hw[256 + (lane << 2)] = ninf;
            hw += W;
            *(float4*)&hw[lane << 2]         = ninf;
            *(float4*)&hw[256 + (lane << 2)] = ninf;
        }
        __syncthreads();                  // the ONLY barrier per batch

        // ---- stage C: vertical van Herk over this 16-row segment ----
        const float* hb = hwbase;
        float Pblk = NEG_INF;
        if (b >= 1) {
#pragma unroll
            for (int r = 0; r < 16; ++r) {
                const float hv = hb[r * W + pos];
                Pblk = fmaxf(Pblk, hv);
                accMax += fmaxf(arr[r], Pblk);
                arr[r] = hv;
            }
        } else {
#pragma unroll
            for (int r = 0; r < 16; ++r) {
                const float hv = hb[r * W + pos];
                Pblk = fmaxf(Pblk, hv);
                arr[r] = hv;
            }
        }
        // segment end: in-place suffix transform arr[r] = max(h[r..15])
#pragma unroll
        for (int rr = 14; rr >= 0; --rr) arr[rr] = fmaxf(arr[rr], arr[rr + 1]);
    }
#undef ROWTAIL

    // ---- block reduction -> per-block partial (plain store, no atomic) ----
    double v = ((double)accMax - (double)accSum) * (1.0 / 9.0);
#pragma unroll
    for (int off = 32; off > 0; off >>= 1) v += __shfl_down(v, off, 64);
    if (lane == 0) wsum[w] = v;
    __syncthreads();
    if (tid == 0) {
        double bsum = 0.0;
#pragma unroll
        for (int wv = 0; wv < 8; ++wv) bsum += wsum[wv];
        partial[id] = bsum;              // written every call: deterministic
    }
}

__global__ __launch_bounds__(512) void finalize_kernel(const double* __restrict__ partial,
                                                       float* __restrict__ out) {
    __shared__ double wsum[8];
    const int tid = threadIdx.x;
    double v = partial[tid];             // 512 partials, one per block
#pragma unroll
    for (int off = 32; off > 0; off >>= 1) v += __shfl_down(v, off, 64);
    if ((tid & 63) == 0) wsum[tid >> 6] = v;
    __syncthreads();
    if (tid == 0) {
        double s = 0.0;
#pragma unroll
        for (int wv = 0; wv < 8; ++wv) s += wsum[wv];
        // total pixels across both tensors = 2*32*512*512 = 16777216
        out[0] = (float)(1.0 - s * (1.0 / 16777216.0));
    }
}

extern "C" void kernel_launch(void* const* d_in, const int* in_sizes, int n_in,
                              void* d_out, int out_size, void* d_ws, size_t ws_size,
                              hipStream_t stream) {
    const float* in0 = (const float*)d_in[0];
    const float* in1 = (const float*)d_in[1];
    float* out = (float*)d_out;
    double* partial = (double*)d_ws;     // 512 doubles = 4 KB

    fused_kernel<<<NBLK, 512, 0, stream>>>(in0, in1, partial);
    finalize_kernel<<<1, 512, 0, stream>>>(partial, out);
}